// Round 1
// baseline (48.138 us; speedup 1.0000x reference)
//
#include <hip/hip_runtime.h>
#include <math.h>

#define S_DIM 2048
#define B_DIM 64
#define F_DIM 512
// output: (B, 3*F) = [last, mean, max]

// Kernel 1: per (s-chunk, batch) partial sum + max over rows s in [c*rpc, min((c+1)*rpc, len))
__global__ __launch_bounds__(128) void scp_partial(const float* __restrict__ x,
                                                   const int* __restrict__ lengths,
                                                   float* __restrict__ ws,
                                                   int rows_per_chunk, int n_chunks) {
    const int chunk = blockIdx.x;
    const int b = blockIdx.y;
    const int f = threadIdx.x * 4;      // 128 threads x float4 = 512 floats
    const int len = lengths[b];

    int s0 = chunk * rows_per_chunk;
    int s1 = s0 + rows_per_chunk;
    if (s1 > len) s1 = len;

    float4 sum = make_float4(0.f, 0.f, 0.f, 0.f);
    float4 mx = make_float4(-INFINITY, -INFINITY, -INFINITY, -INFINITY);

    const float* base = x + (size_t)b * F_DIM + f;
    const size_t row_stride = (size_t)B_DIM * F_DIM;

    #pragma unroll 4
    for (int s = s0; s < s1; ++s) {
        float4 v = *reinterpret_cast<const float4*>(base + (size_t)s * row_stride);
        sum.x += v.x; sum.y += v.y; sum.z += v.z; sum.w += v.w;
        mx.x = fmaxf(mx.x, v.x);
        mx.y = fmaxf(mx.y, v.y);
        mx.z = fmaxf(mx.z, v.z);
        mx.w = fmaxf(mx.w, v.w);
    }

    float* dst = ws + (size_t)(b * n_chunks + chunk) * (2 * F_DIM);
    *reinterpret_cast<float4*>(dst + f) = sum;
    *reinterpret_cast<float4*>(dst + F_DIM + f) = mx;
}

// Kernel 2: combine chunk partials, fetch last row, write [last, mean, max]
__global__ __launch_bounds__(128) void scp_finalize(const float* __restrict__ x,
                                                    const int* __restrict__ lengths,
                                                    const float* __restrict__ ws,
                                                    float* __restrict__ out,
                                                    int n_chunks) {
    const int b = blockIdx.x;
    const int f = threadIdx.x * 4;
    const int len = lengths[b];

    float4 sum = make_float4(0.f, 0.f, 0.f, 0.f);
    float4 mx = make_float4(-INFINITY, -INFINITY, -INFINITY, -INFINITY);

    for (int c = 0; c < n_chunks; ++c) {
        const float* src = ws + (size_t)(b * n_chunks + c) * (2 * F_DIM);
        float4 s4 = *reinterpret_cast<const float4*>(src + f);
        float4 m4 = *reinterpret_cast<const float4*>(src + F_DIM + f);
        sum.x += s4.x; sum.y += s4.y; sum.z += s4.z; sum.w += s4.w;
        mx.x = fmaxf(mx.x, m4.x);
        mx.y = fmaxf(mx.y, m4.y);
        mx.z = fmaxf(mx.z, m4.z);
        mx.w = fmaxf(mx.w, m4.w);
    }

    // last = x[len-1, b, :]
    const float4 last = *reinterpret_cast<const float4*>(
        x + ((size_t)(len - 1) * B_DIM + b) * F_DIM + f);

    const float inv = 1.0f / (float)len;
    float4 mean = make_float4(sum.x * inv, sum.y * inv, sum.z * inv, sum.w * inv);

    float* ob = out + (size_t)b * (3 * F_DIM);
    *reinterpret_cast<float4*>(ob + f) = last;
    *reinterpret_cast<float4*>(ob + F_DIM + f) = mean;
    *reinterpret_cast<float4*>(ob + 2 * F_DIM + f) = mx;
}

extern "C" void kernel_launch(void* const* d_in, const int* in_sizes, int n_in,
                              void* d_out, int out_size, void* d_ws, size_t ws_size,
                              hipStream_t stream) {
    const float* x = (const float*)d_in[0];
    const int* lengths = (const int*)d_in[1];
    float* out = (float*)d_out;
    float* ws = (float*)d_ws;

    int n_chunks = 64;
    size_t need = (size_t)B_DIM * n_chunks * 2 * F_DIM * sizeof(float);
    while (n_chunks > 1 && need > ws_size) { n_chunks >>= 1; need >>= 1; }
    int rpc = (S_DIM + n_chunks - 1) / n_chunks;

    scp_partial<<<dim3(n_chunks, B_DIM), 128, 0, stream>>>(x, lengths, ws, rpc, n_chunks);
    scp_finalize<<<B_DIM, 128, 0, stream>>>(x, lengths, ws, out, n_chunks);
}

// Round 2
// 34.833 us; speedup vs baseline: 1.3820x; 1.3820x over previous
//
#include <hip/hip_runtime.h>
#include <math.h>

#define S_DIM 2048
#define B_DIM 64
#define F_DIM 512
// output: (B, 3*F) = [last, mean, max]

// Kernel 1: per (chunk, batch) partial sum + max over INTERLEAVED rows
// s = chunk + n_chunks * j, j = 0..ceil((len-chunk)/n_chunks)-1.
// Interleaving makes every chunk of a batch do the same number of rows
// (+-1), so block work is balanced regardless of lengths[].
__global__ __launch_bounds__(128) void scp_partial(const float* __restrict__ x,
                                                   const int* __restrict__ lengths,
                                                   float* __restrict__ ws,
                                                   int n_chunks) {
    const int c = blockIdx.x;
    const int b = blockIdx.y;
    const int f = threadIdx.x * 4;      // 128 threads x float4 = 512 floats
    const int len = lengths[b];

    float4 sum = make_float4(0.f, 0.f, 0.f, 0.f);
    float4 mx = make_float4(-INFINITY, -INFINITY, -INFINITY, -INFINITY);

    const size_t row_stride = (size_t)B_DIM * F_DIM;
    const float* p = x + (size_t)c * row_stride + (size_t)b * F_DIM + f;
    const size_t step = (size_t)n_chunks * row_stride;

    const int cnt = (len > c) ? (len - c + n_chunks - 1) / n_chunks : 0;

    #pragma unroll 4
    for (int j = 0; j < cnt; ++j) {
        float4 v = *reinterpret_cast<const float4*>(p);
        sum.x += v.x; sum.y += v.y; sum.z += v.z; sum.w += v.w;
        mx.x = fmaxf(mx.x, v.x);
        mx.y = fmaxf(mx.y, v.y);
        mx.z = fmaxf(mx.z, v.z);
        mx.w = fmaxf(mx.w, v.w);
        p += step;
    }

    float* dst = ws + (size_t)(b * n_chunks + c) * (2 * F_DIM);
    *reinterpret_cast<float4*>(dst + f) = sum;
    *reinterpret_cast<float4*>(dst + F_DIM + f) = mx;
}

// Kernel 2: combine chunk partials (chunk-parallel, LDS reduce), fetch last
// row, write [last, mean, max]. Grid (B, 4): block (b,y) owns features
// [y*128, (y+1)*128). 128 threads = 32 float4-groups x 4-way chunk split.
__global__ __launch_bounds__(128) void scp_finalize(const float* __restrict__ x,
                                                    const int* __restrict__ lengths,
                                                    const float* __restrict__ ws,
                                                    float* __restrict__ out,
                                                    int n_chunks) {
    const int b = blockIdx.x;
    const int y = blockIdx.y;           // feature quarter
    const int tid = threadIdx.x;
    const int f4l = tid & 31;           // 32 float4 groups = 128 floats
    const int cpar = tid >> 5;          // 0..3 chunk-split lane
    const int f = y * 128 + f4l * 4;

    float4 sum = make_float4(0.f, 0.f, 0.f, 0.f);
    float4 mx = make_float4(-INFINITY, -INFINITY, -INFINITY, -INFINITY);

    for (int c = cpar; c < n_chunks; c += 4) {
        const float* src = ws + (size_t)(b * n_chunks + c) * (2 * F_DIM);
        float4 s4 = *reinterpret_cast<const float4*>(src + f);
        float4 m4 = *reinterpret_cast<const float4*>(src + F_DIM + f);
        sum.x += s4.x; sum.y += s4.y; sum.z += s4.z; sum.w += s4.w;
        mx.x = fmaxf(mx.x, m4.x);
        mx.y = fmaxf(mx.y, m4.y);
        mx.z = fmaxf(mx.z, m4.z);
        mx.w = fmaxf(mx.w, m4.w);
    }

    __shared__ float4 ssum[4][32];
    __shared__ float4 smax[4][32];
    ssum[cpar][f4l] = sum;
    smax[cpar][f4l] = mx;
    __syncthreads();

    if (cpar == 0) {
        for (int k = 1; k < 4; ++k) {
            float4 s4 = ssum[k][f4l];
            float4 m4 = smax[k][f4l];
            sum.x += s4.x; sum.y += s4.y; sum.z += s4.z; sum.w += s4.w;
            mx.x = fmaxf(mx.x, m4.x);
            mx.y = fmaxf(mx.y, m4.y);
            mx.z = fmaxf(mx.z, m4.z);
            mx.w = fmaxf(mx.w, m4.w);
        }

        const int len = lengths[b];
        const float4 last = *reinterpret_cast<const float4*>(
            x + ((size_t)(len - 1) * B_DIM + b) * F_DIM + f);
        const float inv = 1.0f / (float)len;
        float4 mean = make_float4(sum.x * inv, sum.y * inv, sum.z * inv, sum.w * inv);

        float* ob = out + (size_t)b * (3 * F_DIM);
        *reinterpret_cast<float4*>(ob + f) = last;
        *reinterpret_cast<float4*>(ob + F_DIM + f) = mean;
        *reinterpret_cast<float4*>(ob + 2 * F_DIM + f) = mx;
    }
}

extern "C" void kernel_launch(void* const* d_in, const int* in_sizes, int n_in,
                              void* d_out, int out_size, void* d_ws, size_t ws_size,
                              hipStream_t stream) {
    const float* x = (const float*)d_in[0];
    const int* lengths = (const int*)d_in[1];
    float* out = (float*)d_out;
    float* ws = (float*)d_ws;

    int n_chunks = 64;
    size_t need = (size_t)B_DIM * n_chunks * 2 * F_DIM * sizeof(float);
    while (n_chunks > 4 && need > ws_size) { n_chunks >>= 1; need >>= 1; }

    scp_partial<<<dim3(n_chunks, B_DIM), 128, 0, stream>>>(x, lengths, ws, n_chunks);
    scp_finalize<<<dim3(B_DIM, 4), 128, 0, stream>>>(x, lengths, ws, out, n_chunks);
}